// Round 3
// baseline (230.122 us; speedup 1.0000x reference)
//
#include <hip/hip_runtime.h>

#define BATCH 100000

__device__ __forceinline__ float relu(float v) { return fmaxf(v, 0.f); }

// 4 lanes per sample. Lane t of a quad:
//   phi: neighbors [4t, 4t+4)   (linearity: per-lane partial acc, shuffle-summed)
//   obs: observations [2t, 2t+2)
//   rho/psi: hidden units [16t, 16t+16) (partial r/e, shuffle-summed)
__global__ __launch_bounds__(256, 8) void barrier_net(
    const float* __restrict__ x,
    const float* __restrict__ phi_w1, const float* __restrict__ phi_b1,
    const float* __restrict__ phi_w2, const float* __restrict__ phi_b2,
    const float* __restrict__ obs_w1, const float* __restrict__ obs_b1,
    const float* __restrict__ obs_w2, const float* __restrict__ obs_b2,
    const float* __restrict__ rho_w1, const float* __restrict__ rho_b1,
    const float* __restrict__ rho_w2, const float* __restrict__ rho_b2,
    const float* __restrict__ psi_w1, const float* __restrict__ psi_b1,
    const float* __restrict__ psi_w2, const float* __restrict__ psi_b2,
    float2* __restrict__ out)
{
    const int tid = blockIdx.x * 256 + threadIdx.x;
    const int s = tid >> 2;
    const int t = tid & 3;
    if (s >= BATCH) return;
    const float* xr = x + (size_t)s * 85;

    // ---- per-lane slice of the sample ----
    float nb[4][4];                      // my 4 neighbors
    const int nbase = 5 + 16 * t;
#pragma unroll
    for (int n = 0; n < 4; ++n)
#pragma unroll
        for (int k = 0; k < 4; ++k)
            nb[n][k] = xr[nbase + 4 * n + k];

    float ob[2][2];                      // my 2 observations
    const int obase = 69 + 4 * t;
    ob[0][0] = xr[obase];     ob[0][1] = xr[obase + 1];
    ob[1][0] = xr[obase + 2]; ob[1][1] = xr[obase + 3];

    const float g0 = xr[0], g1 = xr[1];

    // ---- barrier partial over my neighbors ----
    float bar0 = 0.f, bar1 = 0.f;
#pragma unroll
    for (int n = 0; n < 4; ++n) {
        float p0 = -nb[n][0], p1 = -nb[n][1];
        float r  = __builtin_amdgcn_sqrtf(fmaf(p0, p0, p1 * p1));
        float sc = 0.01f * __builtin_amdgcn_rcpf(r - 0.2f);
        bar0 = fmaf(sc, p0, bar0);
        bar1 = fmaf(sc, p1, bar1);
    }

    // ---- acc partial: each lane carries 1/4 of the bias (pairwise tree sum is exact for equal values) ----
    float acc[16];
#pragma unroll
    for (int j = 0; j < 16; ++j)
        acc[j] = fmaf(4.f, phi_b2[j], 2.f * obs_b2[j]);

    // ---- phi: my 4 neighbors, all 64 h (weights wave-uniform -> SGPR) ----
#pragma unroll 4
    for (int h = 0; h < 64; ++h) {
        float w0 = phi_w1[h], w1 = phi_w1[64 + h], w2 = phi_w1[128 + h], w3 = phi_w1[192 + h];
        float b  = phi_b1[h];
        float hs = relu(fmaf(nb[0][0], w0, fmaf(nb[0][1], w1, fmaf(nb[0][2], w2, fmaf(nb[0][3], w3, b)))))
                 + relu(fmaf(nb[1][0], w0, fmaf(nb[1][1], w1, fmaf(nb[1][2], w2, fmaf(nb[1][3], w3, b)))))
                 + relu(fmaf(nb[2][0], w0, fmaf(nb[2][1], w1, fmaf(nb[2][2], w2, fmaf(nb[2][3], w3, b)))))
                 + relu(fmaf(nb[3][0], w0, fmaf(nb[3][1], w1, fmaf(nb[3][2], w2, fmaf(nb[3][3], w3, b)))));
#pragma unroll
        for (int j = 0; j < 16; ++j)
            acc[j] = fmaf(hs, phi_w2[h * 16 + j], acc[j]);
    }

    // ---- obs: my 2 observations, all 64 h ----
#pragma unroll 4
    for (int h = 0; h < 64; ++h) {
        float w0 = obs_w1[h], w1 = obs_w1[64 + h];
        float b  = obs_b1[h];
        float hs = relu(fmaf(ob[0][0], w0, fmaf(ob[0][1], w1, b)))
                 + relu(fmaf(ob[1][0], w0, fmaf(ob[1][1], w1, b)));
#pragma unroll
        for (int j = 0; j < 16; ++j)
            acc[j] = fmaf(hs, obs_w2[h * 16 + j], acc[j]);
    }

    // ---- quad tree-sum: acc + barrier ----
#pragma unroll
    for (int j = 0; j < 16; ++j) {
        acc[j] += __shfl_xor(acc[j], 1);
        acc[j] += __shfl_xor(acc[j], 2);
    }
    bar0 += __shfl_xor(bar0, 1); bar0 += __shfl_xor(bar0, 2);
    bar1 += __shfl_xor(bar1, 1); bar1 += __shfl_xor(bar1, 2);

    // ---- rho: my 16 hidden units ----
    float r0 = 0.f, r1 = 0.f;
    {
        const float* rw1 = rho_w1 + 16 * t;   // [j*64 + i]
        const float* rw2 = rho_w2 + 32 * t;   // [2i + c]
        const float* rb1 = rho_b1 + 16 * t;
#pragma unroll 2
        for (int i = 0; i < 16; ++i) {
            float tt = rb1[i];
#pragma unroll
            for (int j = 0; j < 16; ++j)
                tt = fmaf(acc[j], rw1[j * 64 + i], tt);
            tt = relu(tt);
            r0 = fmaf(tt, rw2[2 * i],     r0);
            r1 = fmaf(tt, rw2[2 * i + 1], r1);
        }
    }
    r0 += __shfl_xor(r0, 1); r0 += __shfl_xor(r0, 2);
    r1 += __shfl_xor(r1, 1); r1 += __shfl_xor(r1, 2);
    r0 += rho_b2[0];
    r1 += rho_b2[1];

    // ---- psi: my 16 hidden units ----
    float e0 = 0.f, e1 = 0.f;
    {
        const float* pw1 = psi_w1 + 16 * t;   // [k*64 + i]
        const float* pw2 = psi_w2 + 32 * t;
        const float* pb1 = psi_b1 + 16 * t;
#pragma unroll 2
        for (int i = 0; i < 16; ++i) {
            float tt = fmaf(r0, pw1[i],
                       fmaf(r1, pw1[64 + i],
                       fmaf(g0, pw1[128 + i],
                       fmaf(g1, pw1[192 + i], pb1[i]))));
            tt = relu(tt);
            e0 = fmaf(tt, pw2[2 * i],     e0);
            e1 = fmaf(tt, pw2[2 * i + 1], e1);
        }
    }
    e0 += __shfl_xor(e0, 1); e0 += __shfl_xor(e0, 2);
    e1 += __shfl_xor(e1, 1); e1 += __shfl_xor(e1, 2);
    e0 += psi_b2[0];
    e1 += psi_b2[1];

    if (t == 0) {
        float a0 = tanhf(tanhf(e0) + bar0);
        float a1 = tanhf(tanhf(e1) + bar1);
        out[s] = make_float2(2.f * a0, 2.f * a1);
    }
}

extern "C" void kernel_launch(void* const* d_in, const int* in_sizes, int n_in,
                              void* d_out, int out_size, void* d_ws, size_t ws_size,
                              hipStream_t stream) {
    const int threads = BATCH * 4;
    dim3 grid((threads + 255) / 256), block(256);
    barrier_net<<<grid, block, 0, stream>>>(
        (const float*)d_in[0],
        (const float*)d_in[1],  (const float*)d_in[2],  (const float*)d_in[3],  (const float*)d_in[4],
        (const float*)d_in[5],  (const float*)d_in[6],  (const float*)d_in[7],  (const float*)d_in[8],
        (const float*)d_in[9],  (const float*)d_in[10], (const float*)d_in[11], (const float*)d_in[12],
        (const float*)d_in[13], (const float*)d_in[14], (const float*)d_in[15], (const float*)d_in[16],
        (float2*)d_out);
}

// Round 4
// 197.963 us; speedup vs baseline: 1.1624x; 1.1624x over previous
//
#include <hip/hip_runtime.h>

#define BATCH 100000

__device__ __forceinline__ float relu(float v) { return fmaxf(v, 0.f); }

// 4 lanes per sample. Lane t of a quad:
//   phi: neighbors [4t, 4t+4)   (linearity: per-lane partial acc, shuffle-summed)
//   obs: observations [2t, 2t+2)
//   rho/psi: hidden units [16t, 16t+16) (partial r/e, shuffle-summed)
// launch_bounds(256,4): 128-VGPR cap. (256,8) capped at 64 VGPR and spilled
// acc[16] to scratch (R3: WRITE_SIZE +25.6MB = 400k lanes x 16 floats).
__global__ __launch_bounds__(256, 4) void barrier_net(
    const float* __restrict__ x,
    const float* __restrict__ phi_w1, const float* __restrict__ phi_b1,
    const float* __restrict__ phi_w2, const float* __restrict__ phi_b2,
    const float* __restrict__ obs_w1, const float* __restrict__ obs_b1,
    const float* __restrict__ obs_w2, const float* __restrict__ obs_b2,
    const float* __restrict__ rho_w1, const float* __restrict__ rho_b1,
    const float* __restrict__ rho_w2, const float* __restrict__ rho_b2,
    const float* __restrict__ psi_w1, const float* __restrict__ psi_b1,
    const float* __restrict__ psi_w2, const float* __restrict__ psi_b2,
    float2* __restrict__ out)
{
    const int tid = blockIdx.x * 256 + threadIdx.x;
    const int s = tid >> 2;
    const int t = tid & 3;
    if (s >= BATCH) return;
    const float* xr = x + (size_t)s * 85;

    // ---- per-lane slice of the sample ----
    float nb[4][4];                      // my 4 neighbors
    const int nbase = 5 + 16 * t;
#pragma unroll
    for (int n = 0; n < 4; ++n)
#pragma unroll
        for (int k = 0; k < 4; ++k)
            nb[n][k] = xr[nbase + 4 * n + k];

    float ob[2][2];                      // my 2 observations
    const int obase = 69 + 4 * t;
    ob[0][0] = xr[obase];     ob[0][1] = xr[obase + 1];
    ob[1][0] = xr[obase + 2]; ob[1][1] = xr[obase + 3];

    const float g0 = xr[0], g1 = xr[1];

    // ---- barrier partial over my neighbors ----
    float bar0 = 0.f, bar1 = 0.f;
#pragma unroll
    for (int n = 0; n < 4; ++n) {
        float p0 = -nb[n][0], p1 = -nb[n][1];
        float r  = __builtin_amdgcn_sqrtf(fmaf(p0, p0, p1 * p1));
        float sc = 0.01f * __builtin_amdgcn_rcpf(r - 0.2f);
        bar0 = fmaf(sc, p0, bar0);
        bar1 = fmaf(sc, p1, bar1);
    }

    // ---- acc partial: each lane carries 1/4 of the bias (pairwise tree sum is exact for equal values) ----
    float acc[16];
#pragma unroll
    for (int j = 0; j < 16; ++j)
        acc[j] = fmaf(4.f, phi_b2[j], 2.f * obs_b2[j]);

    // ---- phi: my 4 neighbors, all 64 h (weights wave-uniform -> SGPR) ----
#pragma unroll 4
    for (int h = 0; h < 64; ++h) {
        float w0 = phi_w1[h], w1 = phi_w1[64 + h], w2 = phi_w1[128 + h], w3 = phi_w1[192 + h];
        float b  = phi_b1[h];
        float hs = relu(fmaf(nb[0][0], w0, fmaf(nb[0][1], w1, fmaf(nb[0][2], w2, fmaf(nb[0][3], w3, b)))))
                 + relu(fmaf(nb[1][0], w0, fmaf(nb[1][1], w1, fmaf(nb[1][2], w2, fmaf(nb[1][3], w3, b)))))
                 + relu(fmaf(nb[2][0], w0, fmaf(nb[2][1], w1, fmaf(nb[2][2], w2, fmaf(nb[2][3], w3, b)))))
                 + relu(fmaf(nb[3][0], w0, fmaf(nb[3][1], w1, fmaf(nb[3][2], w2, fmaf(nb[3][3], w3, b)))));
#pragma unroll
        for (int j = 0; j < 16; ++j)
            acc[j] = fmaf(hs, phi_w2[h * 16 + j], acc[j]);
    }

    // ---- obs: my 2 observations, all 64 h ----
#pragma unroll 4
    for (int h = 0; h < 64; ++h) {
        float w0 = obs_w1[h], w1 = obs_w1[64 + h];
        float b  = obs_b1[h];
        float hs = relu(fmaf(ob[0][0], w0, fmaf(ob[0][1], w1, b)))
                 + relu(fmaf(ob[1][0], w0, fmaf(ob[1][1], w1, b)));
#pragma unroll
        for (int j = 0; j < 16; ++j)
            acc[j] = fmaf(hs, obs_w2[h * 16 + j], acc[j]);
    }

    // ---- quad tree-sum: acc + barrier ----
#pragma unroll
    for (int j = 0; j < 16; ++j) {
        acc[j] += __shfl_xor(acc[j], 1);
        acc[j] += __shfl_xor(acc[j], 2);
    }
    bar0 += __shfl_xor(bar0, 1); bar0 += __shfl_xor(bar0, 2);
    bar1 += __shfl_xor(bar1, 1); bar1 += __shfl_xor(bar1, 2);

    // ---- rho: my 16 hidden units ----
    float r0 = 0.f, r1 = 0.f;
    {
        const float* rw1 = rho_w1 + 16 * t;   // [j*64 + i]
        const float* rw2 = rho_w2 + 32 * t;   // [2i + c]
        const float* rb1 = rho_b1 + 16 * t;
#pragma unroll 2
        for (int i = 0; i < 16; ++i) {
            float tt = rb1[i];
#pragma unroll
            for (int j = 0; j < 16; ++j)
                tt = fmaf(acc[j], rw1[j * 64 + i], tt);
            tt = relu(tt);
            r0 = fmaf(tt, rw2[2 * i],     r0);
            r1 = fmaf(tt, rw2[2 * i + 1], r1);
        }
    }
    r0 += __shfl_xor(r0, 1); r0 += __shfl_xor(r0, 2);
    r1 += __shfl_xor(r1, 1); r1 += __shfl_xor(r1, 2);
    r0 += rho_b2[0];
    r1 += rho_b2[1];

    // ---- psi: my 16 hidden units ----
    float e0 = 0.f, e1 = 0.f;
    {
        const float* pw1 = psi_w1 + 16 * t;   // [k*64 + i]
        const float* pw2 = psi_w2 + 32 * t;
        const float* pb1 = psi_b1 + 16 * t;
#pragma unroll 2
        for (int i = 0; i < 16; ++i) {
            float tt = fmaf(r0, pw1[i],
                       fmaf(r1, pw1[64 + i],
                       fmaf(g0, pw1[128 + i],
                       fmaf(g1, pw1[192 + i], pb1[i]))));
            tt = relu(tt);
            e0 = fmaf(tt, pw2[2 * i],     e0);
            e1 = fmaf(tt, pw2[2 * i + 1], e1);
        }
    }
    e0 += __shfl_xor(e0, 1); e0 += __shfl_xor(e0, 2);
    e1 += __shfl_xor(e1, 1); e1 += __shfl_xor(e1, 2);
    e0 += psi_b2[0];
    e1 += psi_b2[1];

    if (t == 0) {
        float a0 = tanhf(tanhf(e0) + bar0);
        float a1 = tanhf(tanhf(e1) + bar1);
        out[s] = make_float2(2.f * a0, 2.f * a1);
    }
}

extern "C" void kernel_launch(void* const* d_in, const int* in_sizes, int n_in,
                              void* d_out, int out_size, void* d_ws, size_t ws_size,
                              hipStream_t stream) {
    const int threads = BATCH * 4;
    dim3 grid((threads + 255) / 256), block(256);
    barrier_net<<<grid, block, 0, stream>>>(
        (const float*)d_in[0],
        (const float*)d_in[1],  (const float*)d_in[2],  (const float*)d_in[3],  (const float*)d_in[4],
        (const float*)d_in[5],  (const float*)d_in[6],  (const float*)d_in[7],  (const float*)d_in[8],
        (const float*)d_in[9],  (const float*)d_in[10], (const float*)d_in[11], (const float*)d_in[12],
        (const float*)d_in[13], (const float*)d_in[14], (const float*)d_in[15], (const float*)d_in[16],
        (float2*)d_out);
}

// Round 5
// 153.117 us; speedup vs baseline: 1.5029x; 1.2929x over previous
//
#include <hip/hip_runtime.h>

#define BATCH 100000

typedef float v2 __attribute__((ext_vector_type(2)));

__device__ __forceinline__ v2 fma2(v2 a, v2 b, v2 c) { return __builtin_elementwise_fma(a, b, c); }
__device__ __forceinline__ v2 relu2(v2 a) { v2 z = {0.f, 0.f}; return __builtin_elementwise_max(a, z); }
__device__ __forceinline__ v2 splat(float a) { v2 r = {a, a}; return r; }
__device__ __forceinline__ v2 ldv2(const float* p) { return *(const v2*)p; }
__device__ __forceinline__ float relu(float v) { return fmaxf(v, 0.f); }

// 4 lanes per sample. Lane t: phi neighbors [4t,4t+4), obs [2t,2t+2)
// (linearity: per-lane partial acc, DPP-shuffle-summed). rho/psi are
// DUPLICATED across the quad (R4 showed the lane-split version's
// lane-dependent weight loads -> ~350 VMEM/lane L1 chains = 66% stall).
// All weights wave-uniform -> s_load; hidden units processed in pairs
// (float2) -> v_pk_fma_f32 halves VALU issue.
__global__ __launch_bounds__(256, 4) void barrier_net(
    const float* __restrict__ x,
    const float* __restrict__ phi_w1, const float* __restrict__ phi_b1,
    const float* __restrict__ phi_w2, const float* __restrict__ phi_b2,
    const float* __restrict__ obs_w1, const float* __restrict__ obs_b1,
    const float* __restrict__ obs_w2, const float* __restrict__ obs_b2,
    const float* __restrict__ rho_w1, const float* __restrict__ rho_b1,
    const float* __restrict__ rho_w2, const float* __restrict__ rho_b2,
    const float* __restrict__ psi_w1, const float* __restrict__ psi_b1,
    const float* __restrict__ psi_w2, const float* __restrict__ psi_b2,
    float2* __restrict__ out)
{
    const int tid = blockIdx.x * 256 + threadIdx.x;
    const int s = tid >> 2;
    const int t = tid & 3;
    if (s >= BATCH) return;
    const float* xr = x + (size_t)s * 85;

    // ---- per-lane slice of the sample ----
    float nb[4][4];                      // my 4 neighbors
    const int nbase = 5 + 16 * t;
#pragma unroll
    for (int n = 0; n < 4; ++n)
#pragma unroll
        for (int k = 0; k < 4; ++k)
            nb[n][k] = xr[nbase + 4 * n + k];

    float ob[2][2];                      // my 2 observations
    const int obase = 69 + 4 * t;
    ob[0][0] = xr[obase];     ob[0][1] = xr[obase + 1];
    ob[1][0] = xr[obase + 2]; ob[1][1] = xr[obase + 3];

    const float g0 = xr[0], g1 = xr[1];

    // ---- barrier partial over my neighbors ----
    float bar0 = 0.f, bar1 = 0.f;
#pragma unroll
    for (int n = 0; n < 4; ++n) {
        float p0 = -nb[n][0], p1 = -nb[n][1];
        float r  = __builtin_amdgcn_sqrtf(fmaf(p0, p0, p1 * p1));
        float sc = 0.01f * __builtin_amdgcn_rcpf(r - 0.2f);
        bar0 = fmaf(sc, p0, bar0);
        bar1 = fmaf(sc, p1, bar1);
    }

    // ---- acc (16 values as 8 float2), per-lane quarter of the bias ----
    v2 acc[8];
#pragma unroll
    for (int p = 0; p < 8; ++p)
        acc[p] = fma2(splat(4.f), ldv2(phi_b2 + 2 * p),
                 fma2(splat(2.f), ldv2(obs_b2 + 2 * p), splat(0.f)));

    // ---- phi: my 4 neighbors, hidden units in pairs ----
#pragma unroll 2
    for (int hp = 0; hp < 32; ++hp) {
        const int h = 2 * hp;
        v2 w0 = ldv2(phi_w1 + h),       w1 = ldv2(phi_w1 + 64 + h);
        v2 w2 = ldv2(phi_w1 + 128 + h), w3 = ldv2(phi_w1 + 192 + h);
        v2 b  = ldv2(phi_b1 + h);
        v2 hs = {0.f, 0.f};
#pragma unroll
        for (int n = 0; n < 4; ++n) {
            v2 tv = fma2(splat(nb[n][0]), w0,
                    fma2(splat(nb[n][1]), w1,
                    fma2(splat(nb[n][2]), w2,
                    fma2(splat(nb[n][3]), w3, b))));
            hs += relu2(tv);
        }
        const float* w2r0 = phi_w2 + (size_t)h * 16;
        v2 hx = splat(hs.x), hy = splat(hs.y);
#pragma unroll
        for (int p = 0; p < 8; ++p)
            acc[p] = fma2(hy, ldv2(w2r0 + 16 + 2 * p),
                     fma2(hx, ldv2(w2r0 + 2 * p), acc[p]));
    }

    // ---- obs: my 2 observations ----
#pragma unroll 2
    for (int hp = 0; hp < 32; ++hp) {
        const int h = 2 * hp;
        v2 w0 = ldv2(obs_w1 + h), w1 = ldv2(obs_w1 + 64 + h);
        v2 b  = ldv2(obs_b1 + h);
        v2 hs = relu2(fma2(splat(ob[0][0]), w0, fma2(splat(ob[0][1]), w1, b)))
              + relu2(fma2(splat(ob[1][0]), w0, fma2(splat(ob[1][1]), w1, b)));
        const float* w2r0 = obs_w2 + (size_t)h * 16;
        v2 hx = splat(hs.x), hy = splat(hs.y);
#pragma unroll
        for (int p = 0; p < 8; ++p)
            acc[p] = fma2(hy, ldv2(w2r0 + 16 + 2 * p),
                     fma2(hx, ldv2(w2r0 + 2 * p), acc[p]));
    }

    // ---- quad tree-sum: acc + barrier (DPP shuffles) ----
#pragma unroll
    for (int p = 0; p < 8; ++p) {
        float a0 = acc[p].x, a1 = acc[p].y;
        a0 += __shfl_xor(a0, 1); a0 += __shfl_xor(a0, 2);
        a1 += __shfl_xor(a1, 1); a1 += __shfl_xor(a1, 2);
        acc[p].x = a0; acc[p].y = a1;
    }
    bar0 += __shfl_xor(bar0, 1); bar0 += __shfl_xor(bar0, 2);
    bar1 += __shfl_xor(bar1, 1); bar1 += __shfl_xor(bar1, 2);

    // ---- rho: 16 -> 64 -> 2, duplicated across quad, uniform weights ----
    v2 rr = ldv2(rho_b2);                // (r0, r1)
#pragma unroll 2
    for (int hp = 0; hp < 32; ++hp) {
        const int h = 2 * hp;
        v2 tt = ldv2(rho_b1 + h);
#pragma unroll
        for (int j = 0; j < 8; ++j) {
            tt = fma2(splat(acc[j].x), ldv2(rho_w1 + (size_t)(2 * j) * 64 + h), tt);
            tt = fma2(splat(acc[j].y), ldv2(rho_w1 + (size_t)(2 * j + 1) * 64 + h), tt);
        }
        tt = relu2(tt);
        rr = fma2(splat(tt.x), ldv2(rho_w2 + 2 * h), rr);
        rr = fma2(splat(tt.y), ldv2(rho_w2 + 2 * h + 2), rr);
    }

    // ---- psi: [r0, r1, g0, g1] -> 64 -> 2, duplicated, uniform weights ----
    v2 ee = ldv2(psi_b2);
#pragma unroll 2
    for (int hp = 0; hp < 32; ++hp) {
        const int h = 2 * hp;
        v2 tt = fma2(splat(rr.x), ldv2(psi_w1 + h),
                fma2(splat(rr.y), ldv2(psi_w1 + 64 + h),
                fma2(splat(g0),   ldv2(psi_w1 + 128 + h),
                fma2(splat(g1),   ldv2(psi_w1 + 192 + h), ldv2(psi_b1 + h)))));
        tt = relu2(tt);
        ee = fma2(splat(tt.x), ldv2(psi_w2 + 2 * h), ee);
        ee = fma2(splat(tt.y), ldv2(psi_w2 + 2 * h + 2), ee);
    }

    if (t == 0) {
        float a0 = tanhf(tanhf(ee.x) + bar0);
        float a1 = tanhf(tanhf(ee.y) + bar1);
        out[s] = make_float2(2.f * a0, 2.f * a1);
    }
}

extern "C" void kernel_launch(void* const* d_in, const int* in_sizes, int n_in,
                              void* d_out, int out_size, void* d_ws, size_t ws_size,
                              hipStream_t stream) {
    const int threads = BATCH * 4;
    dim3 grid((threads + 255) / 256), block(256);
    barrier_net<<<grid, block, 0, stream>>>(
        (const float*)d_in[0],
        (const float*)d_in[1],  (const float*)d_in[2],  (const float*)d_in[3],  (const float*)d_in[4],
        (const float*)d_in[5],  (const float*)d_in[6],  (const float*)d_in[7],  (const float*)d_in[8],
        (const float*)d_in[9],  (const float*)d_in[10], (const float*)d_in[11], (const float*)d_in[12],
        (const float*)d_in[13], (const float*)d_in[14], (const float*)d_in[15], (const float*)d_in[16],
        (float2*)d_out);
}